// Round 6
// baseline (212.284 us; speedup 1.0000x reference)
//
#include <hip/hip_runtime.h>
#include <cstdint>
#include <cstddef>

// ---------------------------------------------------------------------------
// MHA bf16-MFMA pipeline, round 13.
//   flash rewritten around the LDS-pipe bottleneck (r12 analysis: 11.3 MB/CU
//   LDS traffic @85B/cyc == 55.4us == measured):
//     - 32x32x16 MFMA, swapped QK^T (A=K,B=Q): P stays in registers,
//       B-frag for PV assembled via packbf2 + permlane32_swap (VALU, no LDS)
//     - 32 q/wave x 4 waves (128 q/block, 512 blocks), K/V frag-major
//       staging (linear, written by gemm_proj epilogue), dist-2 reg prefetch
//     - per-CU LDS traffic ~5 MB -> ~25us floor
//   gemm_proj: unchanged except K(z==1)/V(z==2) epilogue writes frag-major
//   per-64-tile layout: off = head*131072 + tile*4096 + f*512 + j*8.
// ---------------------------------------------------------------------------

typedef unsigned short bf16_t;
typedef __attribute__((ext_vector_type(8))) short short8;   // MFMA A/B frag (8 bf16)
typedef __attribute__((ext_vector_type(4))) float f32x4;
typedef __attribute__((ext_vector_type(16))) float f32x16;  // 32x32 MFMA C/D
typedef __attribute__((ext_vector_type(2))) unsigned int uint2v;

__device__ __forceinline__ uint32_t fbits(float f) {
  union { float f; uint32_t u; } v; v.f = f; return v.u;
}
__device__ __forceinline__ bf16_t f2bf(float f) {          // RNE
  uint32_t u = fbits(f);
  return (bf16_t)((u + 0x7FFFu + ((u >> 16) & 1u)) >> 16);
}
// pack 2 floats -> 2 bf16 (round-half-up): 2 adds + 1 v_perm
__device__ __forceinline__ uint32_t packbf2(float lo, float hi) {
  uint32_t a = fbits(hi) + 0x8000u;
  uint32_t b = fbits(lo) + 0x8000u;
  return __builtin_amdgcn_perm(a, b, 0x07060302u);         // {lo.hi16, hi.hi16}
}
__device__ __forceinline__ int4 cvt8(f32x4 lo, f32x4 hi) { // 8 f32 -> 8 bf16
  return make_int4((int)packbf2(lo.x, lo.y), (int)packbf2(lo.z, lo.w),
                   (int)packbf2(hi.x, hi.y), (int)packbf2(hi.z, hi.w));
}

// async global->LDS, 16B per lane. LDS dest = uniform base + lane*16.
__device__ __forceinline__ void gload16(const bf16_t* g, bf16_t* l) {
  __builtin_amdgcn_global_load_lds(
      (const __attribute__((address_space(1))) void*)g,
      (__attribute__((address_space(3))) void*)l, 16, 0, 0);
}

// ---- prep: Wo cast + tiled transpose of W_{q,k,v} + q/k/v bf16 cast --------
__global__ void prep_kernel(const float* __restrict__ Wo,
                            const float* __restrict__ Wq, const float* __restrict__ Wk,
                            const float* __restrict__ Wv,
                            const float* __restrict__ q, const float* __restrict__ k,
                            const float* __restrict__ v,
                            bf16_t* __restrict__ Woo,
                            bf16_t* __restrict__ Wtq, bf16_t* __restrict__ Wtk,
                            bf16_t* __restrict__ Wtv,
                            bf16_t* __restrict__ qb, bf16_t* __restrict__ kb,
                            bf16_t* __restrict__ vb) {
  int blk = blockIdx.x;
  int tid = threadIdx.x;
  if (blk < 1024) {                          // Wo f32 -> bf16 (1M elems)
    int i = blk * 256 + tid;
    f32x4 val = ((const f32x4*)Wo)[i];
    ushort4 o;
    o.x = f2bf(val.x); o.y = f2bf(val.y); o.z = f2bf(val.z); o.w = f2bf(val.w);
    ((ushort4*)Woo)[i] = o;
  } else if (blk < 2560) {
    // W[16,1024,64] -> Wt[h*64+dk][d], tile = one head x 32 d-rows
    int blk2 = blk - 1024;                   // [0, 1536)
    int z = blk2 >> 9, t = blk2 & 511;       // 3 x 512
    const float* W = z == 0 ? Wq : z == 1 ? Wk : Wv;
    bf16_t* Wt = z == 0 ? Wtq : z == 1 ? Wtk : Wtv;
    int h = t >> 5, d0 = (t & 31) * 32;
    __shared__ float tile[32][65];
    const float* src = W + ((size_t)h << 16) + (size_t)d0 * 64;
    int d = tid >> 3;
#pragma unroll
    for (int j = 0; j < 2; j++) {
      int dk = (tid & 7) * 8 + j * 4;
      *(f32x4*)&tile[d][dk] = *(const f32x4*)(src + d * 64 + dk);
    }
    __syncthreads();
    int dk2 = tid >> 2, c = tid & 3;
    union { ushort s[8]; int4 v; } o;
#pragma unroll
    for (int j = 0; j < 8; j++) o.s[j] = f2bf(tile[c * 8 + j][dk2]);
    *(int4*)(Wt + (size_t)(h * 64 + dk2) * 1024 + d0 + c * 8) = o.v;
  } else {
    // q/k/v f32 -> bf16, 8 elems/thread
    int blk3 = blk - 2560;                   // [0, 6144)
    int z = blk3 >> 11;                      // 3 x 2048 blocks
    int t3 = blk3 & 2047;
    const float* src = z == 0 ? q : z == 1 ? k : v;
    bf16_t* dst = z == 0 ? qb : z == 1 ? kb : vb;
    int i = t3 * 256 + tid;                  // 8-elem chunk id
    f32x4 lo = ((const f32x4*)src)[i * 2];
    f32x4 hi = ((const f32x4*)src)[i * 2 + 1];
    ((int4*)dst)[i] = cvt8(lo, hi);
  }
}

// ---- batched projection GEMM: global_load_lds staging, XCD-swizzled grid ---
// z==0 -> qh row-major; z==1 -> kh frag-major; z==2 -> vh frag-major.
// frag-major per head: off = tile*4096 + f*512 + j*8 (tile = k-row/64 for K,
// k-col/64 for V; f = (mi|dmi)*4 + (dk|ks); j = half*32 + (row&31)).
__global__ __launch_bounds__(256) void gemm_proj_kernel(
    const bf16_t* __restrict__ A0, const bf16_t* __restrict__ A1, const bf16_t* __restrict__ A2,
    const bf16_t* __restrict__ B0, const bf16_t* __restrict__ B1, const bf16_t* __restrict__ B2,
    bf16_t* __restrict__ O0, bf16_t* __restrict__ O1, bf16_t* __restrict__ O2,
    float s0)
{
  const int bid = blockIdx.x;
  const int nIdx = bid / 96;
  const int g = bid - nIdx * 96;
  const int z = g % 3;
  const int m0 = (g / 3) * 128, n0 = nIdx * 128;

  const bf16_t* A  = z == 0 ? A0 : z == 1 ? A1 : A2;
  const bf16_t* Bt = z == 0 ? B0 : z == 1 ? B1 : B2;
  bf16_t* Cout     = z == 0 ? O0 : z == 1 ? O1 : O2;
  const float scale = z == 0 ? s0 : 1.0f;
  const int K = 1024;

  __shared__ alignas(16) bf16_t smem[18432];

  const int tid = threadIdx.x;
  const int lane = tid & 63, wave = tid >> 6;
  const int wm = wave >> 1, wn = wave & 1;
  const int quad = lane >> 4, l15 = lane & 15;

  f32x4 acc[4][4];
#pragma unroll
  for (int i = 0; i < 4; i++)
#pragma unroll
    for (int j = 0; j < 4; j++) acc[i][j] = (f32x4)0.0f;

  const int srow = tid >> 2, scol = (tid & 3) * 8;
  const bf16_t* pa0 = A  + (size_t)(m0 + srow) * K + scol;
  const bf16_t* pa1 = pa0 + (size_t)64 * K;
  const bf16_t* pb0 = Bt + (size_t)(n0 + srow) * K + scol;
  const bf16_t* pb1 = pb0 + (size_t)64 * K;
  const int lws = wave * 512;              // uniform chunk base (elems)

  gload16(pa0, smem + lws);
  gload16(pa1, smem + 2048 + lws);
  gload16(pb0, smem + 4096 + lws);
  gload16(pb1, smem + 6144 + lws);
  __syncthreads();

  for (int it = 0; it < 32; ++it) {
    const int cur = (it & 1) * 8192;
    if (it < 31) {                         // async prefetch next K-tile
      const int nxt = ((it + 1) & 1) * 8192;
      const int ko = (it + 1) * 32;
      gload16(pa0 + ko, smem + nxt + lws);
      gload16(pa1 + ko, smem + nxt + 2048 + lws);
      gload16(pb0 + ko, smem + nxt + 4096 + lws);
      gload16(pb1 + ko, smem + nxt + 6144 + lws);
    }

    short8 af[4], bfr[4];
#pragma unroll
    for (int mi = 0; mi < 4; mi++)
      af[mi] = *(const short8*)(smem + cur + (wm * 64 + mi * 16 + l15) * 32 + quad * 8);
#pragma unroll
    for (int ni = 0; ni < 4; ni++)
      bfr[ni] = *(const short8*)(smem + cur + 4096 + (wn * 64 + ni * 16 + l15) * 32 + quad * 8);
#pragma unroll
    for (int mi = 0; mi < 4; mi++)
#pragma unroll
      for (int ni = 0; ni < 4; ni++)
        acc[mi][ni] = __builtin_amdgcn_mfma_f32_16x16x32_bf16(af[mi], bfr[ni], acc[mi][ni], 0, 0, 0);

    __syncthreads();
  }

  const int s0r = m0 & 2047, bb = m0 >> 11, hp = n0 >> 6;
  if (z < 2) {
    bf16_t* slot = smem + wn * 9216;
#pragma unroll
    for (int ni = 0; ni < 4; ni++)
#pragma unroll
      for (int mi = 0; mi < 4; mi++)
#pragma unroll
        for (int r = 0; r < 4; r++)
          slot[(wm * 64 + mi * 16 + quad * 4 + r) * 72 + ni * 16 + l15] =
              f2bf(acc[mi][ni][r] * scale);
    __syncthreads();
#pragma unroll
    for (int rd = 0; rd < 8; ++rd) {
      int idx = rd * 256 + tid;
      int si = idx >> 10, mm = (idx >> 3) & 127, c8 = idx & 7;
      int4 val = *(const int4*)(smem + si * 9216 + mm * 72 + c8 * 8);
      size_t head = (size_t)(bb * 16 + hp + si);
      if (z == 0) {                        // q row-major
        *(int4*)(Cout + (head * 2048 + s0r + mm) * 64 + c8 * 8) = val;
      } else {                             // k frag-major
        int row = s0r + mm;
        int tile = row >> 6, loc = row & 63;
        int f = (loc >> 5) * 4 + (c8 >> 1);
        int j = (c8 & 1) * 32 + (loc & 31);
        *(int4*)(Cout + head * 131072 + (size_t)tile * 4096 + f * 512 + j * 8) = val;
      }
    }
  } else {
    bf16_t* slot = smem + wn * 8704;
#pragma unroll
    for (int ni = 0; ni < 4; ni++)
#pragma unroll
      for (int mi = 0; mi < 4; mi++) {
        uint2 pk = make_uint2(packbf2(acc[mi][ni][0], acc[mi][ni][1]),
                              packbf2(acc[mi][ni][2], acc[mi][ni][3]));
        *(uint2*)(slot + (ni * 16 + l15) * 136 + wm * 64 + mi * 16 + quad * 4) = pk;
      }
    __syncthreads();
#pragma unroll
    for (int rd = 0; rd < 8; ++rd) {
      int idx = rd * 256 + tid;
      int si = idx >> 10, c = (idx >> 4) & 63, ck = idx & 15;
      int4 val = *(const int4*)(smem + si * 8704 + c * 136 + ck * 8);
      int kk = s0r + ck * 8;               // v frag-major: d=c, k=kk
      int tile = kk >> 6;
      int f = (c >> 5) * 4 + ((kk >> 4) & 3);
      int j = ((kk >> 3) & 1) * 32 + (c & 31);
      *(int4*)(Cout + (size_t)(bb * 16 + hp + si) * 131072 + (size_t)tile * 4096 + f * 512 + j * 8) = val;
    }
  }
}

// ---- final GEMM: 128(M) x 64(N), global_load_lds staging, XCD swizzle ------
__global__ __launch_bounds__(256) void gemm_out_kernel(
    const bf16_t* __restrict__ A, const bf16_t* __restrict__ Bt,
    float* __restrict__ C, const float* __restrict__ bias)
{
  const int K = 1024, N = 1024;
  __shared__ alignas(16) bf16_t smem[12288];
  const int tid = threadIdx.x;
  const int lane = tid & 63, wave = tid >> 6;
  const int quad = lane >> 4, l15 = lane & 15;
  const int m0 = (blockIdx.x & 31) * 128, n0 = (blockIdx.x >> 5) * 64;

  f32x4 acc[2][4];
#pragma unroll
  for (int i = 0; i < 2; i++)
#pragma unroll
    for (int j = 0; j < 4; j++) acc[i][j] = (f32x4)0.0f;

  const int srow = tid >> 2, scol = (tid & 3) * 8;
  const bf16_t* pa0 = A  + (size_t)(m0 + srow) * K + scol;
  const bf16_t* pa1 = pa0 + (size_t)64 * K;
  const bf16_t* pb  = Bt + (size_t)(n0 + srow) * K + scol;
  const int lws = wave * 512;

  gload16(pa0, smem + lws);
  gload16(pa1, smem + 2048 + lws);
  gload16(pb,  smem + 4096 + lws);
  __syncthreads();

  for (int it = 0; it < 32; ++it) {
    const int cur = (it & 1) * 6144;
    if (it < 31) {
      const int nxt = ((it + 1) & 1) * 6144;
      const int ko = (it + 1) * 32;
      gload16(pa0 + ko, smem + nxt + lws);
      gload16(pa1 + ko, smem + nxt + 2048 + lws);
      gload16(pb + ko,  smem + nxt + 4096 + lws);
    }

    short8 af[2], bfr[4];
#pragma unroll
    for (int mi = 0; mi < 2; mi++)
      af[mi] = *(const short8*)(smem + cur + (wave * 32 + mi * 16 + l15) * 32 + quad * 8);
#pragma unroll
    for (int ni = 0; ni < 4; ni++)
      bfr[ni] = *(const short8*)(smem + cur + 4096 + (ni * 16 + l15) * 32 + quad * 8);
#pragma unroll
    for (int mi = 0; mi < 2; mi++)
#pragma unroll
      for (int ni = 0; ni < 4; ni++)
        acc[mi][ni] = __builtin_amdgcn_mfma_f32_16x16x32_bf16(af[mi], bfr[ni], acc[mi][ni], 0, 0, 0);

    __syncthreads();
  }

#pragma unroll
  for (int ni = 0; ni < 4; ni++) {
    int col = n0 + ni * 16 + l15;
    float bv = bias[col];
#pragma unroll
    for (int mi = 0; mi < 2; mi++) {
      int row = m0 + wave * 32 + mi * 16 + quad * 4;
#pragma unroll
      for (int r = 0; r < 4; r++)
        C[(size_t)(row + r) * N + col] = acc[mi][ni][r] + bv;
    }
  }
}

// ---- flash attention: 32x32 MFMA, in-register P via permlane32_swap --------
// 512 blocks x 4 waves, 32 q/wave. K/V frag-major staged 16KB/tile (dbuf
// 32KB), dist-2 reg prefetch. gid = qi*32 + hb head-colocated XCD grid.
// Layouts (per 64-k tile, frame f = mi*4 + sub, slot j = half*32 + row&31):
//   K: A-frag QK, frame (ki*4 + dk): lane l -> K[ki*32+(l&31)][dk*16+(l>>5)*8+e]
//   V: A-frag PV, frame (di*4 + ks): lane l -> V[di*32+(l&31)][ks*16+(l>>5)*8+e]
// S C/D: q = l&31, k_local = mi*32 + (r&3) + 8*(r>>2) + 4*(l>>5).
// PV B-frag per ks: (d0,d2)=permlane32_swap(pack(p0,p1),pack(p4,p5));
//                   (d1,d3)=permlane32_swap(pack(p2,p3),pack(p6,p7)).
__global__ __launch_bounds__(256) void flash_kernel(
    const bf16_t* __restrict__ qh, const bf16_t* __restrict__ kh,
    const bf16_t* __restrict__ vh, bf16_t* __restrict__ ctx)
{
  __shared__ alignas(16) bf16_t smem[16384];          // {K 4096, V 4096} x 2
  const int tid = threadIdx.x, lane = tid & 63, wave = tid >> 6;
  const int hlf = lane >> 5, l31 = lane & 31;
  const int gid = blockIdx.x;
  const int hb = gid & 31;
  const int h = hb & 15, b = hb >> 4;
  const int q0 = (gid >> 5) * 128;
  const size_t headoff = (size_t)hb * 131072;
  const bf16_t* Q  = qh + headoff;
  const bf16_t* Kf = kh + headoff;
  const bf16_t* Vf = vh + headoff;

  // Q B-frags: col=l31 (q), contraction d = dk*16 + hlf*8 + e
  short8 qf[4];
#pragma unroll
  for (int dk = 0; dk < 4; dk++)
    qf[dk] = *(const short8*)(Q + (size_t)(q0 + wave * 32 + l31) * 64 + dk * 16 + hlf * 8);

  f32x16 Oa = (f32x16)0.0f, Ob = (f32x16)0.0f;
  float lsum = 0.0f;

  // staging: thread covers 16B slots tid and tid+256 for K and V
  const bf16_t* Kp0 = Kf + tid * 8;
  const bf16_t* Kp1 = Kf + tid * 8 + 2048;
  const bf16_t* Vp0 = Vf + 4096 - 4096 + tid * 8;     // same frag space
  const bf16_t* Vp1 = Vf + tid * 8 + 2048;
  bf16_t* sK = smem + tid * 8;
  bf16_t* sV = smem + 4096 + tid * 8;

  auto body = [&](int buf) {
    const bf16_t* Kb = smem + buf * 8192;
    const bf16_t* Vb = smem + buf * 8192 + 4096;
    f32x16 S0 = (f32x16)0.0f, S1 = (f32x16)0.0f;
#pragma unroll
    for (int dk = 0; dk < 4; dk++) {
      short8 kf0 = *(const short8*)(Kb + dk * 512 + lane * 8);
      short8 kf1 = *(const short8*)(Kb + (4 + dk) * 512 + lane * 8);
      S0 = __builtin_amdgcn_mfma_f32_32x32x16_bf16(kf0, qf[dk], S0, 0, 0, 0);
      S1 = __builtin_amdgcn_mfma_f32_32x32x16_bf16(kf1, qf[dk], S1, 0, 0, 0);
    }
#pragma unroll
    for (int r = 0; r < 16; r++) {
      S0[r] = __builtin_amdgcn_exp2f(S0[r]);
      S1[r] = __builtin_amdgcn_exp2f(S1[r]);
    }
    {
      f32x16 ss = S0 + S1;
      float a0 = (ss[0] + ss[1]) + (ss[2] + ss[3]);
      float a1 = (ss[4] + ss[5]) + (ss[6] + ss[7]);
      float a2 = (ss[8] + ss[9]) + (ss[10] + ss[11]);
      float a3 = (ss[12] + ss[13]) + (ss[14] + ss[15]);
      lsum += (a0 + a1) + (a2 + a3);
    }
#pragma unroll
    for (int mi = 0; mi < 2; mi++) {
      f32x16 P = mi ? S1 : S0;
#pragma unroll
      for (int ksl = 0; ksl < 2; ksl++) {
        const int ks = mi * 2 + ksl, base = ksl * 8;
        uint32_t X = packbf2(P[base + 0], P[base + 1]);
        uint32_t Y = packbf2(P[base + 2], P[base + 3]);
        uint32_t Z = packbf2(P[base + 4], P[base + 5]);
        uint32_t W = packbf2(P[base + 6], P[base + 7]);
        uint2v r1 = __builtin_amdgcn_permlane32_swap(X, Z, false, false);
        uint2v r2 = __builtin_amdgcn_permlane32_swap(Y, W, false, false);
        int4 bi = make_int4((int)r1.x, (int)r2.x, (int)r1.y, (int)r2.y);
        short8 Bf = *(short8*)&bi;
        short8 vf0 = *(const short8*)(Vb + ks * 512 + lane * 8);
        short8 vf1 = *(const short8*)(Vb + (4 + ks) * 512 + lane * 8);
        Oa = __builtin_amdgcn_mfma_f32_32x32x16_bf16(vf0, Bf, Oa, 0, 0, 0);
        Ob = __builtin_amdgcn_mfma_f32_32x32x16_bf16(vf1, Bf, Ob, 0, 0, 0);
      }
    }
  };

  // prologue: tile0 -> buf0; tile1 -> regsA
  int4 k0a = *(const int4*)Kp0, k0b = *(const int4*)Kp1;
  int4 v0a = *(const int4*)Vp0, v0b = *(const int4*)Vp1;
  *(int4*)sK = k0a; *(int4*)(sK + 2048) = k0b;
  *(int4*)sV = v0a; *(int4*)(sV + 2048) = v0b;
  int4 kAa = *(const int4*)(Kp0 + 4096), kAb = *(const int4*)(Kp1 + 4096);
  int4 vAa = *(const int4*)(Vp0 + 4096), vAb = *(const int4*)(Vp1 + 4096);
  __syncthreads();

  for (int it = 0; it < 32; it += 2) {
    *(int4*)(sK + 8192) = kAa; *(int4*)(sK + 8192 + 2048) = kAb;
    *(int4*)(sV + 8192) = vAa; *(int4*)(sV + 8192 + 2048) = vAb;
    int4 kBa, kBb, vBa, vBb;
    if (it + 2 < 32) {
      kBa = *(const int4*)(Kp0 + (size_t)(it + 2) * 4096);
      kBb = *(const int4*)(Kp1 + (size_t)(it + 2) * 4096);
      vBa = *(const int4*)(Vp0 + (size_t)(it + 2) * 4096);
      vBb = *(const int4*)(Vp1 + (size_t)(it + 2) * 4096);
    }
    body(0);
    __syncthreads();

    if (it + 2 < 32) {
      *(int4*)sK = kBa; *(int4*)(sK + 2048) = kBb;
      *(int4*)sV = vBa; *(int4*)(sV + 2048) = vBb;
    }
    if (it + 3 < 32) {
      kAa = *(const int4*)(Kp0 + (size_t)(it + 3) * 4096);
      kAb = *(const int4*)(Kp1 + (size_t)(it + 3) * 4096);
      vAa = *(const int4*)(Vp0 + (size_t)(it + 3) * 4096);
      vAb = *(const int4*)(Vp1 + (size_t)(it + 3) * 4096);
    }
    body(1);
    __syncthreads();
  }

  // epilogue: normalize + transpose via (now free) LDS, coalesced ctx write
  lsum += __shfl_xor(lsum, 32, 64);
  float inv = 1.0f / lsum;
  bf16_t* slot = smem + wave * 2048;                  // [32 q][64 d], swizzled
  const int swz = l31 & 7;
#pragma unroll
  for (int dmi = 0; dmi < 2; dmi++) {
    f32x16 Ov = dmi ? Ob : Oa;
#pragma unroll
    for (int rq = 0; rq < 4; rq++) {
      uint2 pk = make_uint2(packbf2(Ov[rq * 4 + 0] * inv, Ov[rq * 4 + 1] * inv),
                            packbf2(Ov[rq * 4 + 2] * inv, Ov[rq * 4 + 3] * inv));
      int c = dmi * 4 + rq;                           // d-chunk (d>>3)
      *(uint2*)(slot + l31 * 64 + ((c ^ swz) * 8 + 4 * hlf)) = pk;
    }
  }
  __syncthreads();
#pragma unroll
  for (int p = 0; p < 4; p++) {
    int s2 = p * 64 + lane;
    int qr = s2 >> 3, cr = s2 & 7;
    int4 val = *(const int4*)(slot + qr * 64 + ((cr ^ (qr & 7)) * 8));
    *(int4*)(ctx + (size_t)(b * 2048 + q0 + wave * 32 + qr) * 1024 + h * 64 + cr * 8) = val;
  }
}

// ---------------------------------------------------------------------------
extern "C" void kernel_launch(void* const* d_in, const int* in_sizes, int n_in,
                              void* d_out, int out_size, void* d_ws, size_t ws_size,
                              hipStream_t stream)
{
  const float* q  = (const float*)d_in[0];
  const float* k  = (const float*)d_in[1];
  const float* v  = (const float*)d_in[2];
  const float* Wq = (const float*)d_in[3];
  const float* Wk = (const float*)d_in[4];
  const float* Wv = (const float*)d_in[5];
  const float* Wo = (const float*)d_in[6];
  const float* bo = (const float*)d_in[7];
  float* out = (float*)d_out;

  const size_t NX = (size_t)4096 * 1024;
  const size_t NW = (size_t)1024 * 1024;

  char* p = (char*)d_ws;
  bf16_t* Wtq = (bf16_t*)p; p += NW * 2;
  bf16_t* Wtk = (bf16_t*)p; p += NW * 2;
  bf16_t* Wtv = (bf16_t*)p; p += NW * 2;
  bf16_t* Wob = (bf16_t*)p; p += NW * 2;
  bf16_t* qb  = (bf16_t*)p; p += NX * 2;
  bf16_t* kb  = (bf16_t*)p; p += NX * 2;
  bf16_t* vb  = (bf16_t*)p; p += NX * 2;
  bf16_t* qhb = (bf16_t*)p; p += NX * 2;
  bf16_t* khb = (bf16_t*)p; p += NX * 2;
  bf16_t* vTb = (bf16_t*)p; p += NX * 2;
  bf16_t* ctxb = (bf16_t*)p; p += NX * 2;

  prep_kernel<<<8704, 256, 0, stream>>>(Wo, Wq, Wk, Wv, q, k, v,
                                        Wob, Wtq, Wtk, Wtv, qb, kb, vb);

  const float qscale = 0.125f * 1.44269504088896340736f;   // 1/sqrt(64) * log2(e)
  gemm_proj_kernel<<<768, 256, 0, stream>>>(qb, kb, vb, Wtq, Wtk, Wtv,
                                            qhb, khb, vTb, qscale);

  flash_kernel<<<512, 256, 0, stream>>>(qhb, khb, vTb, ctxb);

  gemm_out_kernel<<<512, 256, 0, stream>>>(ctxb, Wob, out, bo);

  (void)in_sizes; (void)n_in; (void)out_size; (void)ws_size;
}

// Round 8
// 209.640 us; speedup vs baseline: 1.0126x; 1.0126x over previous
//
#include <hip/hip_runtime.h>
#include <cstdint>
#include <cstddef>

// ---------------------------------------------------------------------------
// MHA bf16-MFMA pipeline, round 15.
//   r14 post-mortem: failed absmax 4.9e-2. Two deltas were shipped at once;
//   this round isolates them. REVERTED: v_cvt_pk_bf16_f32 asm (unverified
//   semantics; guide m240 also says it's slower) -> back to r13-verified
//   packbf2. KEPT: T15 two-tile pipeline (choreography re-derived, no defect
//   found on paper): phase t = {stage(t+1), load(t+2), QK(t) MFMA,
//   softmax(t-1)+PV(t-1) VALU/MFMA, barrier}. K dbuf, V tbuf, SA/SB.
//   prep / gemm_proj / gemm_out: unchanged from r13 (verified).
// ---------------------------------------------------------------------------

typedef unsigned short bf16_t;
typedef __attribute__((ext_vector_type(8))) short short8;   // MFMA A/B frag (8 bf16)
typedef __attribute__((ext_vector_type(4))) float f32x4;
typedef __attribute__((ext_vector_type(16))) float f32x16;  // 32x32 MFMA C/D
typedef __attribute__((ext_vector_type(2))) unsigned int uint2v;

__device__ __forceinline__ uint32_t fbits(float f) {
  union { float f; uint32_t u; } v; v.f = f; return v.u;
}
__device__ __forceinline__ bf16_t f2bf(float f) {          // RNE
  uint32_t u = fbits(f);
  return (bf16_t)((u + 0x7FFFu + ((u >> 16) & 1u)) >> 16);
}
// pack 2 floats -> 2 bf16 (round-half-up): 2 adds + 1 v_perm
__device__ __forceinline__ uint32_t packbf2(float lo, float hi) {
  uint32_t a = fbits(hi) + 0x8000u;
  uint32_t b = fbits(lo) + 0x8000u;
  return __builtin_amdgcn_perm(a, b, 0x07060302u);         // {lo.hi16, hi.hi16}
}
__device__ __forceinline__ int4 cvt8(f32x4 lo, f32x4 hi) { // 8 f32 -> 8 bf16
  return make_int4((int)packbf2(lo.x, lo.y), (int)packbf2(lo.z, lo.w),
                   (int)packbf2(hi.x, hi.y), (int)packbf2(hi.z, hi.w));
}

// async global->LDS, 16B per lane. LDS dest = uniform base + lane*16.
__device__ __forceinline__ void gload16(const bf16_t* g, bf16_t* l) {
  __builtin_amdgcn_global_load_lds(
      (const __attribute__((address_space(1))) void*)g,
      (__attribute__((address_space(3))) void*)l, 16, 0, 0);
}

// ---- prep: Wo cast + tiled transpose of W_{q,k,v} + q/k/v bf16 cast --------
__global__ void prep_kernel(const float* __restrict__ Wo,
                            const float* __restrict__ Wq, const float* __restrict__ Wk,
                            const float* __restrict__ Wv,
                            const float* __restrict__ q, const float* __restrict__ k,
                            const float* __restrict__ v,
                            bf16_t* __restrict__ Woo,
                            bf16_t* __restrict__ Wtq, bf16_t* __restrict__ Wtk,
                            bf16_t* __restrict__ Wtv,
                            bf16_t* __restrict__ qb, bf16_t* __restrict__ kb,
                            bf16_t* __restrict__ vb) {
  int blk = blockIdx.x;
  int tid = threadIdx.x;
  if (blk < 1024) {                          // Wo f32 -> bf16 (1M elems)
    int i = blk * 256 + tid;
    f32x4 val = ((const f32x4*)Wo)[i];
    ushort4 o;
    o.x = f2bf(val.x); o.y = f2bf(val.y); o.z = f2bf(val.z); o.w = f2bf(val.w);
    ((ushort4*)Woo)[i] = o;
  } else if (blk < 2560) {
    // W[16,1024,64] -> Wt[h*64+dk][d], tile = one head x 32 d-rows
    int blk2 = blk - 1024;                   // [0, 1536)
    int z = blk2 >> 9, t = blk2 & 511;       // 3 x 512
    const float* W = z == 0 ? Wq : z == 1 ? Wk : Wv;
    bf16_t* Wt = z == 0 ? Wtq : z == 1 ? Wtk : Wtv;
    int h = t >> 5, d0 = (t & 31) * 32;
    __shared__ float tile[32][65];
    const float* src = W + ((size_t)h << 16) + (size_t)d0 * 64;
    int d = tid >> 3;
#pragma unroll
    for (int j = 0; j < 2; j++) {
      int dk = (tid & 7) * 8 + j * 4;
      *(f32x4*)&tile[d][dk] = *(const f32x4*)(src + d * 64 + dk);
    }
    __syncthreads();
    int dk2 = tid >> 2, c = tid & 3;
    union { ushort s[8]; int4 v; } o;
#pragma unroll
    for (int j = 0; j < 8; j++) o.s[j] = f2bf(tile[c * 8 + j][dk2]);
    *(int4*)(Wt + (size_t)(h * 64 + dk2) * 1024 + d0 + c * 8) = o.v;
  } else {
    // q/k/v f32 -> bf16, 8 elems/thread
    int blk3 = blk - 2560;                   // [0, 6144)
    int z = blk3 >> 11;                      // 3 x 2048 blocks
    int t3 = blk3 & 2047;
    const float* src = z == 0 ? q : z == 1 ? k : v;
    bf16_t* dst = z == 0 ? qb : z == 1 ? kb : vb;
    int i = t3 * 256 + tid;                  // 8-elem chunk id
    f32x4 lo = ((const f32x4*)src)[i * 2];
    f32x4 hi = ((const f32x4*)src)[i * 2 + 1];
    ((int4*)dst)[i] = cvt8(lo, hi);
  }
}

// ---- batched projection GEMM: global_load_lds staging, XCD-swizzled grid ---
// z==0 -> qh row-major; z==1 -> kh frag-major; z==2 -> vh frag-major.
// frag-major per head: off = tile*4096 + f*512 + j*8 (tile = k-row/64 for K,
// k-col/64 for V; f = (mi|dmi)*4 + (dk|ks); j = half*32 + (row&31)).
__global__ __launch_bounds__(256) void gemm_proj_kernel(
    const bf16_t* __restrict__ A0, const bf16_t* __restrict__ A1, const bf16_t* __restrict__ A2,
    const bf16_t* __restrict__ B0, const bf16_t* __restrict__ B1, const bf16_t* __restrict__ B2,
    bf16_t* __restrict__ O0, bf16_t* __restrict__ O1, bf16_t* __restrict__ O2,
    float s0)
{
  const int bid = blockIdx.x;
  const int nIdx = bid / 96;
  const int g = bid - nIdx * 96;
  const int z = g % 3;
  const int m0 = (g / 3) * 128, n0 = nIdx * 128;

  const bf16_t* A  = z == 0 ? A0 : z == 1 ? A1 : A2;
  const bf16_t* Bt = z == 0 ? B0 : z == 1 ? B1 : B2;
  bf16_t* Cout     = z == 0 ? O0 : z == 1 ? O1 : O2;
  const float scale = z == 0 ? s0 : 1.0f;
  const int K = 1024;

  __shared__ alignas(16) bf16_t smem[18432];

  const int tid = threadIdx.x;
  const int lane = tid & 63, wave = tid >> 6;
  const int wm = wave >> 1, wn = wave & 1;
  const int quad = lane >> 4, l15 = lane & 15;

  f32x4 acc[4][4];
#pragma unroll
  for (int i = 0; i < 4; i++)
#pragma unroll
    for (int j = 0; j < 4; j++) acc[i][j] = (f32x4)0.0f;

  const int srow = tid >> 2, scol = (tid & 3) * 8;
  const bf16_t* pa0 = A  + (size_t)(m0 + srow) * K + scol;
  const bf16_t* pa1 = pa0 + (size_t)64 * K;
  const bf16_t* pb0 = Bt + (size_t)(n0 + srow) * K + scol;
  const bf16_t* pb1 = pb0 + (size_t)64 * K;
  const int lws = wave * 512;              // uniform chunk base (elems)

  gload16(pa0, smem + lws);
  gload16(pa1, smem + 2048 + lws);
  gload16(pb0, smem + 4096 + lws);
  gload16(pb1, smem + 6144 + lws);
  __syncthreads();

  for (int it = 0; it < 32; ++it) {
    const int cur = (it & 1) * 8192;
    if (it < 31) {                         // async prefetch next K-tile
      const int nxt = ((it + 1) & 1) * 8192;
      const int ko = (it + 1) * 32;
      gload16(pa0 + ko, smem + nxt + lws);
      gload16(pa1 + ko, smem + nxt + 2048 + lws);
      gload16(pb0 + ko, smem + nxt + 4096 + lws);
      gload16(pb1 + ko, smem + nxt + 6144 + lws);
    }

    short8 af[4], bfr[4];
#pragma unroll
    for (int mi = 0; mi < 4; mi++)
      af[mi] = *(const short8*)(smem + cur + (wm * 64 + mi * 16 + l15) * 32 + quad * 8);
#pragma unroll
    for (int ni = 0; ni < 4; ni++)
      bfr[ni] = *(const short8*)(smem + cur + 4096 + (wn * 64 + ni * 16 + l15) * 32 + quad * 8);
#pragma unroll
    for (int mi = 0; mi < 4; mi++)
#pragma unroll
      for (int ni = 0; ni < 4; ni++)
        acc[mi][ni] = __builtin_amdgcn_mfma_f32_16x16x32_bf16(af[mi], bfr[ni], acc[mi][ni], 0, 0, 0);

    __syncthreads();
  }

  const int s0r = m0 & 2047, bb = m0 >> 11, hp = n0 >> 6;
  if (z < 2) {
    bf16_t* slot = smem + wn * 9216;
#pragma unroll
    for (int ni = 0; ni < 4; ni++)
#pragma unroll
      for (int mi = 0; mi < 4; mi++)
#pragma unroll
        for (int r = 0; r < 4; r++)
          slot[(wm * 64 + mi * 16 + quad * 4 + r) * 72 + ni * 16 + l15] =
              f2bf(acc[mi][ni][r] * scale);
    __syncthreads();
#pragma unroll
    for (int rd = 0; rd < 8; ++rd) {
      int idx = rd * 256 + tid;
      int si = idx >> 10, mm = (idx >> 3) & 127, c8 = idx & 7;
      int4 val = *(const int4*)(smem + si * 9216 + mm * 72 + c8 * 8);
      size_t head = (size_t)(bb * 16 + hp + si);
      if (z == 0) {                        // q row-major
        *(int4*)(Cout + (head * 2048 + s0r + mm) * 64 + c8 * 8) = val;
      } else {                             // k frag-major
        int row = s0r + mm;
        int tile = row >> 6, loc = row & 63;
        int f = (loc >> 5) * 4 + (c8 >> 1);
        int j = (c8 & 1) * 32 + (loc & 31);
        *(int4*)(Cout + head * 131072 + (size_t)tile * 4096 + f * 512 + j * 8) = val;
      }
    }
  } else {
    bf16_t* slot = smem + wn * 8704;
#pragma unroll
    for (int ni = 0; ni < 4; ni++)
#pragma unroll
      for (int mi = 0; mi < 4; mi++) {
        uint2 pk = make_uint2(packbf2(acc[mi][ni][0], acc[mi][ni][1]),
                              packbf2(acc[mi][ni][2], acc[mi][ni][3]));
        *(uint2*)(slot + (ni * 16 + l15) * 136 + wm * 64 + mi * 16 + quad * 4) = pk;
      }
    __syncthreads();
#pragma unroll
    for (int rd = 0; rd < 8; ++rd) {
      int idx = rd * 256 + tid;
      int si = idx >> 10, c = (idx >> 4) & 63, ck = idx & 15;
      int4 val = *(const int4*)(smem + si * 8704 + c * 136 + ck * 8);
      int kk = s0r + ck * 8;               // v frag-major: d=c, k=kk
      int tile = kk >> 6;
      int f = (c >> 5) * 4 + ((kk >> 4) & 3);
      int j = ((kk >> 3) & 1) * 32 + (c & 31);
      *(int4*)(Cout + (size_t)(bb * 16 + hp + si) * 131072 + (size_t)tile * 4096 + f * 512 + j * 8) = val;
    }
  }
}

// ---- final GEMM: 128(M) x 64(N), global_load_lds staging, XCD swizzle ------
__global__ __launch_bounds__(256) void gemm_out_kernel(
    const bf16_t* __restrict__ A, const bf16_t* __restrict__ Bt,
    float* __restrict__ C, const float* __restrict__ bias)
{
  const int K = 1024, N = 1024;
  __shared__ alignas(16) bf16_t smem[12288];
  const int tid = threadIdx.x;
  const int lane = tid & 63, wave = tid >> 6;
  const int quad = lane >> 4, l15 = lane & 15;
  const int m0 = (blockIdx.x & 31) * 128, n0 = (blockIdx.x >> 5) * 64;

  f32x4 acc[2][4];
#pragma unroll
  for (int i = 0; i < 2; i++)
#pragma unroll
    for (int j = 0; j < 4; j++) acc[i][j] = (f32x4)0.0f;

  const int srow = tid >> 2, scol = (tid & 3) * 8;
  const bf16_t* pa0 = A  + (size_t)(m0 + srow) * K + scol;
  const bf16_t* pa1 = pa0 + (size_t)64 * K;
  const bf16_t* pb  = Bt + (size_t)(n0 + srow) * K + scol;
  const int lws = wave * 512;

  gload16(pa0, smem + lws);
  gload16(pa1, smem + 2048 + lws);
  gload16(pb,  smem + 4096 + lws);
  __syncthreads();

  for (int it = 0; it < 32; ++it) {
    const int cur = (it & 1) * 6144;
    if (it < 31) {
      const int nxt = ((it + 1) & 1) * 6144;
      const int ko = (it + 1) * 32;
      gload16(pa0 + ko, smem + nxt + lws);
      gload16(pa1 + ko, smem + nxt + 2048 + lws);
      gload16(pb + ko,  smem + nxt + 4096 + lws);
    }

    short8 af[2], bfr[4];
#pragma unroll
    for (int mi = 0; mi < 2; mi++)
      af[mi] = *(const short8*)(smem + cur + (wave * 32 + mi * 16 + l15) * 32 + quad * 8);
#pragma unroll
    for (int ni = 0; ni < 4; ni++)
      bfr[ni] = *(const short8*)(smem + cur + 4096 + (ni * 16 + l15) * 32 + quad * 8);
#pragma unroll
    for (int mi = 0; mi < 2; mi++)
#pragma unroll
      for (int ni = 0; ni < 4; ni++)
        acc[mi][ni] = __builtin_amdgcn_mfma_f32_16x16x32_bf16(af[mi], bfr[ni], acc[mi][ni], 0, 0, 0);

    __syncthreads();
  }

#pragma unroll
  for (int ni = 0; ni < 4; ni++) {
    int col = n0 + ni * 16 + l15;
    float bv = bias[col];
#pragma unroll
    for (int mi = 0; mi < 2; mi++) {
      int row = m0 + wave * 32 + mi * 16 + quad * 4;
#pragma unroll
      for (int r = 0; r < 4; r++)
        C[(size_t)(row + r) * N + col] = acc[mi][ni][r] + bv;
    }
  }
}

// ---- flash attention: 32x32 MFMA, in-register P, T15 two-tile pipeline -----
// 512 blocks x 4 waves, 32 q/wave. Phase t: stage(t+1) | load(t+2) |
// QK(t) MFMA | softmax(t-1) VALU | PV(t-1) MFMA | barrier.
// K double-buffered (2x8KB), V triple-buffered (3x8KB) since PV lags a phase.
// S state double (SA/SB), statically alternated via 2x-unrolled loop.
// P packing: packbf2 (r13-verified; r14's cvt_pk asm reverted).
__global__ __launch_bounds__(256) void flash_kernel(
    const bf16_t* __restrict__ qh, const bf16_t* __restrict__ kh,
    const bf16_t* __restrict__ vh, bf16_t* __restrict__ ctx)
{
  __shared__ alignas(16) bf16_t smem[20480];  // K: [0,8192) dbuf; V: [8192,20480) tbuf
  const int tid = threadIdx.x, lane = tid & 63, wave = tid >> 6;
  const int hlf = lane >> 5, l31 = lane & 31;
  const int gid = blockIdx.x;
  const int hb = gid & 31;
  const int h = hb & 15, b = hb >> 4;
  const int q0 = (gid >> 5) * 128;
  const size_t headoff = (size_t)hb * 131072;
  const bf16_t* Q  = qh + headoff;
  const bf16_t* Kf = kh + headoff;
  const bf16_t* Vf = vh + headoff;

  // Q B-frags: col=l31 (q), contraction d = dk*16 + hlf*8 + e
  short8 qf[4];
#pragma unroll
  for (int dk = 0; dk < 4; dk++)
    qf[dk] = *(const short8*)(Q + (size_t)(q0 + wave * 32 + l31) * 64 + dk * 16 + hlf * 8);

  f32x16 Oa = (f32x16)0.0f, Ob = (f32x16)0.0f;
  f32x16 SA0, SA1, SB0, SB1;
  float lsum = 0.0f;

  const bf16_t* Kp0 = Kf + tid * 8;
  const bf16_t* Kp1 = Kf + tid * 8 + 2048;
  const bf16_t* Vp0 = Vf + tid * 8;
  const bf16_t* Vp1 = Vf + tid * 8 + 2048;
  bf16_t* const sKw = smem + tid * 8;            // + kbuf*4096
  bf16_t* const sVw = smem + 8192 + tid * 8;     // + vbuf*4096

  auto qk = [&](f32x16& S0, f32x16& S1, const bf16_t* Kb) {
    S0 = (f32x16)0.0f; S1 = (f32x16)0.0f;
#pragma unroll
    for (int dk = 0; dk < 4; dk++) {
      short8 kf0 = *(const short8*)(Kb + dk * 512 + lane * 8);
      short8 kf1 = *(const short8*)(Kb + (4 + dk) * 512 + lane * 8);
      S0 = __builtin_amdgcn_mfma_f32_32x32x16_bf16(kf0, qf[dk], S0, 0, 0, 0);
      S1 = __builtin_amdgcn_mfma_f32_32x32x16_bf16(kf1, qf[dk], S1, 0, 0, 0);
    }
  };

  auto softpv = [&](f32x16& S0, f32x16& S1, const bf16_t* Vb) {
#pragma unroll
    for (int r = 0; r < 16; r++) {
      S0[r] = __builtin_amdgcn_exp2f(S0[r]);
      S1[r] = __builtin_amdgcn_exp2f(S1[r]);
    }
    {
      f32x16 ss = S0 + S1;
      float a0 = (ss[0] + ss[1]) + (ss[2] + ss[3]);
      float a1 = (ss[4] + ss[5]) + (ss[6] + ss[7]);
      float a2 = (ss[8] + ss[9]) + (ss[10] + ss[11]);
      float a3 = (ss[12] + ss[13]) + (ss[14] + ss[15]);
      lsum += (a0 + a1) + (a2 + a3);
    }
#pragma unroll
    for (int mi = 0; mi < 2; mi++) {
      const f32x16& P = mi ? S1 : S0;
#pragma unroll
      for (int ksl = 0; ksl < 2; ksl++) {
        const int ks = mi * 2 + ksl, base = ksl * 8;
        uint32_t X = packbf2(P[base + 0], P[base + 1]);
        uint32_t Y = packbf2(P[base + 2], P[base + 3]);
        uint32_t Z = packbf2(P[base + 4], P[base + 5]);
        uint32_t W = packbf2(P[base + 6], P[base + 7]);
        uint2v r1 = __builtin_amdgcn_permlane32_swap(X, Z, false, false);
        uint2v r2 = __builtin_amdgcn_permlane32_swap(Y, W, false, false);
        int4 bi = make_int4((int)r1.x, (int)r2.x, (int)r1.y, (int)r2.y);
        short8 Bf = *(short8*)&bi;
        short8 vf0 = *(const short8*)(Vb + ks * 512 + lane * 8);
        short8 vf1 = *(const short8*)(Vb + (4 + ks) * 512 + lane * 8);
        Oa = __builtin_amdgcn_mfma_f32_32x32x16_bf16(vf0, Bf, Oa, 0, 0, 0);
        Ob = __builtin_amdgcn_mfma_f32_32x32x16_bf16(vf1, Bf, Ob, 0, 0, 0);
      }
    }
  };

  // prologue: tile0 -> kbuf0/vbuf0 (direct); tile1 -> regsA
  {
    int4 k0a = *(const int4*)Kp0, k0b = *(const int4*)Kp1;
    int4 v0a = *(const int4*)Vp0, v0b = *(const int4*)Vp1;
    *(int4*)sKw = k0a; *(int4*)(sKw + 2048) = k0b;
    *(int4*)sVw = v0a; *(int4*)(sVw + 2048) = v0b;
  }
  int4 kAa = *(const int4*)(Kp0 + 4096), kAb = *(const int4*)(Kp1 + 4096);
  int4 vAa = *(const int4*)(Vp0 + 4096), vAb = *(const int4*)(Vp1 + 4096);
  __syncthreads();

  // phase 0: stage tile1 (regsA) -> kbuf1/vbuf1; load tile2 -> regsB; QK(0)
  *(int4*)(sKw + 4096) = kAa; *(int4*)(sKw + 4096 + 2048) = kAb;
  *(int4*)(sVw + 4096) = vAa; *(int4*)(sVw + 4096 + 2048) = vAb;
  int4 kBa = *(const int4*)(Kp0 + 8192), kBb = *(const int4*)(Kp1 + 8192);
  int4 vBa = *(const int4*)(Vp0 + 8192), vBb = *(const int4*)(Vp1 + 8192);
  qk(SA0, SA1, smem);                                  // tile0 from kbuf0
  __syncthreads();

  // main loop: phases (t odd, t+1 even) for t = 1..29; vbuf rotor:
  // at loop top m0=(t-1)%3, m1=t%3, m2=(t+1)%3
  int m0 = 0, m1 = 1, m2 = 2;
  for (int t = 1; t < 31; t += 2) {
    // phase t (odd): stage tile t+1 (regsB) -> kbuf0 / vbuf m2; load t+2 -> A
    *(int4*)sKw = kBa; *(int4*)(sKw + 2048) = kBb;
    *(int4*)(sVw + m2 * 4096) = vBa; *(int4*)(sVw + m2 * 4096 + 2048) = vBb;
    {
      const size_t ko = (size_t)(t + 2) * 4096;
      kAa = *(const int4*)(Kp0 + ko); kAb = *(const int4*)(Kp1 + ko);
      vAa = *(const int4*)(Vp0 + ko); vAb = *(const int4*)(Vp1 + ko);
    }
    qk(SB0, SB1, smem + 4096);                         // tile t from kbuf1
    softpv(SA0, SA1, smem + 8192 + m0 * 4096);         // tile t-1
    __syncthreads();

    // phase t+1 (even): stage tile t+2 (regsA) -> kbuf1 / vbuf m0; load t+3 -> B
    *(int4*)(sKw + 4096) = kAa; *(int4*)(sKw + 4096 + 2048) = kAb;
    *(int4*)(sVw + m0 * 4096) = vAa; *(int4*)(sVw + m0 * 4096 + 2048) = vAb;
    if (t + 3 < 32) {
      const size_t ko = (size_t)(t + 3) * 4096;
      kBa = *(const int4*)(Kp0 + ko); kBb = *(const int4*)(Kp1 + ko);
      vBa = *(const int4*)(Vp0 + ko); vBb = *(const int4*)(Vp1 + ko);
    }
    qk(SA0, SA1, smem);                                // tile t+1 from kbuf0
    softpv(SB0, SB1, smem + 8192 + m1 * 4096);         // tile t
    __syncthreads();

    int tmp = m2; m2 = m1; m1 = m0; m0 = tmp;          // rotate for t += 2
  }
  // phase 31: QK(31) from kbuf1; softmax/PV of tile 30 (vbuf m0 = 30%3 = 0)
  qk(SB0, SB1, smem + 4096);
  softpv(SA0, SA1, smem + 8192 + m0 * 4096);
  __syncthreads();
  // epilogue phase: softmax/PV of tile 31 (vbuf 31%3 = 1)
  softpv(SB0, SB1, smem + 8192 + m1 * 4096);

  // normalize + transpose via LDS [0,8192) (kbufs dead after last barrier)
  lsum += __shfl_xor(lsum, 32, 64);
  float inv = 1.0f / lsum;
  bf16_t* slot = smem + wave * 2048;                   // [32 q][64 d], swizzled
  const int swz = l31 & 7;
#pragma unroll
  for (int dmi = 0; dmi < 2; dmi++) {
    const f32x16& Ov = dmi ? Ob : Oa;
#pragma unroll
    for (int rq = 0; rq < 4; rq++) {
      uint2 pk = make_uint2(packbf2(Ov[rq * 4 + 0] * inv, Ov[rq * 4 + 1] * inv),
                            packbf2(Ov[rq * 4 + 2] * inv, Ov[rq * 4 + 3] * inv));
      int c = dmi * 4 + rq;                            // d-chunk (d>>3)
      *(uint2*)(slot + l31 * 64 + ((c ^ swz) * 8 + 4 * hlf)) = pk;
    }
  }
  __syncthreads();
#pragma unroll
  for (int p = 0; p < 4; p++) {
    int s2 = p * 64 + lane;
    int qr = s2 >> 3, cr = s2 & 7;
    int4 val = *(const int4*)(slot + qr * 64 + ((cr ^ (qr & 7)) * 8));
    *(int4*)(ctx + (size_t)(b * 2048 + q0 + wave * 32 + qr) * 1024 + h * 64 + cr * 8) = val;
  }
}

// ---------------------------------------------------------------------------
extern "C" void kernel_launch(void* const* d_in, const int* in_sizes, int n_in,
                              void* d_out, int out_size, void* d_ws, size_t ws_size,
                              hipStream_t stream)
{
  const float* q  = (const float*)d_in[0];
  const float* k  = (const float*)d_in[1];
  const float* v  = (const float*)d_in[2];
  const float* Wq = (const float*)d_in[3];
  const float* Wk = (const float*)d_in[4];
  const float* Wv = (const float*)d_in[5];
  const float* Wo = (const float*)d_in[6];
  const float* bo = (const float*)d_in[7];
  float* out = (float*)d_out;

  const size_t NX = (size_t)4096 * 1024;
  const size_t NW = (size_t)1024 * 1024;

  char* p = (char*)d_ws;
  bf16_t* Wtq = (bf16_t*)p; p += NW * 2;
  bf16_t* Wtk = (bf16_t*)p; p += NW * 2;
  bf16_t* Wtv = (bf16_t*)p; p += NW * 2;
  bf16_t* Wob = (bf16_t*)p; p += NW * 2;
  bf16_t* qb  = (bf16_t*)p; p += NX * 2;
  bf16_t* kb  = (bf16_t*)p; p += NX * 2;
  bf16_t* vb  = (bf16_t*)p; p += NX * 2;
  bf16_t* qhb = (bf16_t*)p; p += NX * 2;
  bf16_t* khb = (bf16_t*)p; p += NX * 2;
  bf16_t* vTb = (bf16_t*)p; p += NX * 2;
  bf16_t* ctxb = (bf16_t*)p; p += NX * 2;

  prep_kernel<<<8704, 256, 0, stream>>>(Wo, Wq, Wk, Wv, q, k, v,
                                        Wob, Wtq, Wtk, Wtv, qb, kb, vb);

  const float qscale = 0.125f * 1.44269504088896340736f;   // 1/sqrt(64) * log2(e)
  gemm_proj_kernel<<<768, 256, 0, stream>>>(qb, kb, vb, Wtq, Wtk, Wtv,
                                            qhb, khb, vTb, qscale);

  flash_kernel<<<512, 256, 0, stream>>>(qhb, khb, vTb, ctxb);

  gemm_out_kernel<<<512, 256, 0, stream>>>(ctxb, Wob, out, bo);

  (void)in_sizes; (void)n_in; (void)out_size; (void)ws_size;
}